// Round 4
// baseline (312.545 us; speedup 1.0000x reference)
//
#include <hip/hip_runtime.h>

typedef unsigned short ushort_t;
typedef unsigned int uint_t;

typedef float f32x4_t __attribute__((ext_vector_type(4)));
typedef short s16x8_t __attribute__((ext_vector_type(8)));

#define NB   256   // B
#define NG   512   // 2*B graphs
#define NPG  24    // nodes per graph
#define NMAXI 32   // N_MAX
#define EPG  200   // edges per graph
#define DD   256   // feature dim
// 1/TEMPERATURE * log2(e) = 10 * 1.4426950408889634
#define L2E_OVER_T 14.426950408889634f

// padded index for ru/rv: 64-float chunks at stride 68 (4-bank shift per chunk)
#define PADIDX(i) ((((i) >> 6) * 68) + ((i) & 63))

__device__ __forceinline__ ushort_t f2bf(float f) {
    uint_t u = __float_as_uint(f);
    u += 0x7FFFu + ((u >> 16) & 1u);        // round-to-nearest-even
    return (ushort_t)(u >> 16);
}
__device__ __forceinline__ float bfhi(uint_t u) { return __uint_as_float(u & 0xFFFF0000u); }
__device__ __forceinline__ float bflo(uint_t u) { return __uint_as_float(u << 16); }

__device__ __forceinline__ float frcp(float x) {
#if __has_builtin(__builtin_amdgcn_rcpf)
    return __builtin_amdgcn_rcpf(x);
#else
    return 1.0f / x;
#endif
}

// ---------------------------------------------------------------------------
// Kernel A: W1,W2 -> bf16 transposed ([n][k]), via LDS transpose.
// ---------------------------------------------------------------------------
__global__ __launch_bounds__(256) void prep_w(const float* __restrict__ W1,
                                              const float* __restrict__ W2,
                                              ushort_t* __restrict__ W1T,
                                              ushort_t* __restrict__ W2T)
{
    __shared__ float tile[2][4 * 256];
    const int t = threadIdx.x;
    const int k0 = blockIdx.x * 4;
    #pragma unroll
    for (int i = t; i < 4 * 256; i += 256) {
        tile[0][i] = W1[k0 * 256 + i];
        tile[1][i] = W2[k0 * 256 + i];
    }
    __syncthreads();
    const int n = t;
    #pragma unroll
    for (int m = 0; m < 2; ++m) {
        uint_t p0 = (uint_t)f2bf(tile[m][0 * 256 + n]) | ((uint_t)f2bf(tile[m][1 * 256 + n]) << 16);
        uint_t p1 = (uint_t)f2bf(tile[m][2 * 256 + n]) | ((uint_t)f2bf(tile[m][3 * 256 + n]) << 16);
        ushort_t* dst = (m ? W2T : W1T) + n * 256 + k0;
        uint2 pk; pk.x = p0; pk.y = p1;
        *(uint2*)dst = pk;
    }
}

// ---------------------------------------------------------------------------
// Kernel B: fused 2-layer MLP on the 12288 surviving edge rows (rank < 24).
// ---------------------------------------------------------------------------
__global__ __launch_bounds__(256) void mlp_kernel(
    const float* __restrict__ X, const ushort_t* __restrict__ W1T,
    const ushort_t* __restrict__ W2T, const float* __restrict__ b1,
    const float* __restrict__ b2, float* __restrict__ Y)
{
    __shared__ ushort_t sA[64 * 272];
    const int t = threadIdx.x;
    const int blk = blockIdx.x;
    const int lane = t & 63;
    const int w = t >> 6;
    const int quad = lane >> 4;
    const int mrow = lane & 15;

    {
        int r = t >> 2;
        int ch = (t & 3) * 64;
        int rho = blk * 64 + r;
        int g = rho / NPG;
        int e = rho - g * NPG;
        const float* src = X + ((size_t)(g * EPG + e)) * DD + ch;
        ushort_t* dst = &sA[r * 272 + ch];
        #pragma unroll
        for (int i = 0; i < 8; ++i) {
            float4 v0 = *(const float4*)(src + i * 8);
            float4 v1 = *(const float4*)(src + i * 8 + 4);
            uint4 pk;
            pk.x = (uint_t)f2bf(v0.x) | ((uint_t)f2bf(v0.y) << 16);
            pk.y = (uint_t)f2bf(v0.z) | ((uint_t)f2bf(v0.w) << 16);
            pk.z = (uint_t)f2bf(v1.x) | ((uint_t)f2bf(v1.y) << 16);
            pk.w = (uint_t)f2bf(v1.z) | ((uint_t)f2bf(v1.w) << 16);
            *(uint4*)(dst + i * 8) = pk;
        }
    }
    __syncthreads();

    f32x4_t acc[16];
    #pragma unroll
    for (int i = 0; i < 16; ++i) acc[i] = (f32x4_t){0.f, 0.f, 0.f, 0.f};

    #pragma unroll
    for (int k0 = 0; k0 < 256; k0 += 32) {
        s16x8_t a[4], bb[4];
        #pragma unroll
        for (int mt = 0; mt < 4; ++mt)
            a[mt] = *(const s16x8_t*)&sA[(mt * 16 + mrow) * 272 + k0 + quad * 8];
        #pragma unroll
        for (int nt = 0; nt < 4; ++nt)
            bb[nt] = *(const s16x8_t*)(W1T + (size_t)(64 * w + nt * 16 + mrow) * 256 + k0 + quad * 8);
        #pragma unroll
        for (int mt = 0; mt < 4; ++mt) {
            #pragma unroll
            for (int nt = 0; nt < 4; ++nt)
                acc[mt * 4 + nt] = __builtin_amdgcn_mfma_f32_16x16x32_bf16(
                    a[mt], bb[nt], acc[mt * 4 + nt], 0, 0, 0);
        }
    }
    __syncthreads();

    #pragma unroll
    for (int nt = 0; nt < 4; ++nt) {
        int col = 64 * w + nt * 16 + mrow;
        float bias = b1[col];
        #pragma unroll
        for (int mt = 0; mt < 4; ++mt) {
            f32x4_t v = acc[mt * 4 + nt];
            #pragma unroll
            for (int reg = 0; reg < 4; ++reg) {
                int row = mt * 16 + quad * 4 + reg;
                sA[row * 272 + col] = f2bf(fmaxf(v[reg] + bias, 0.f));
            }
        }
    }
    __syncthreads();

    #pragma unroll
    for (int i = 0; i < 16; ++i) acc[i] = (f32x4_t){0.f, 0.f, 0.f, 0.f};

    #pragma unroll
    for (int k0 = 0; k0 < 256; k0 += 32) {
        s16x8_t a[4], bb[4];
        #pragma unroll
        for (int mt = 0; mt < 4; ++mt)
            a[mt] = *(const s16x8_t*)&sA[(mt * 16 + mrow) * 272 + k0 + quad * 8];
        #pragma unroll
        for (int nt = 0; nt < 4; ++nt)
            bb[nt] = *(const s16x8_t*)(W2T + (size_t)(64 * w + nt * 16 + mrow) * 256 + k0 + quad * 8);
        #pragma unroll
        for (int mt = 0; mt < 4; ++mt) {
            #pragma unroll
            for (int nt = 0; nt < 4; ++nt)
                acc[mt * 4 + nt] = __builtin_amdgcn_mfma_f32_16x16x32_bf16(
                    a[mt], bb[nt], acc[mt * 4 + nt], 0, 0, 0);
        }
    }

    #pragma unroll
    for (int nt = 0; nt < 4; ++nt) {
        int col = 64 * w + nt * 16 + mrow;
        float bias = b2[col];
        #pragma unroll
        for (int mt = 0; mt < 4; ++mt) {
            f32x4_t v = acc[mt * 4 + nt];
            #pragma unroll
            for (int reg = 0; reg < 4; ++reg) {
                int row = blk * 64 + mt * 16 + quad * 4 + reg;
                Y[(size_t)row * 256 + col] = v[reg] + bias;
            }
        }
    }
}

// ---------------------------------------------------------------------------
// Kernel C: per-b fused K-build -> 20x linear-domain Sinkhorn -> score.
// Thread (r = t>>2, q = t&3) owns BOTH chunks as packed bf16 (32+32 uints):
//   K  row chunk  K[r][64q..64q+63]    in K32[32]
//   K^T col chunk K[64q..64q+63][r]    in KT32[32]
// amdgpu_waves_per_eu(4,4): firm 128-VGPR budget, ~90 live -> no scratch.
// ---------------------------------------------------------------------------
__global__ __launch_bounds__(1024)
__attribute__((amdgpu_waves_per_eu(4, 4)))
void sink_kernel(
    const float* __restrict__ Tplan, const int* __restrict__ from_idx,
    const int* __restrict__ to_idx, const int* __restrict__ qsz,
    const int* __restrict__ csz, const float* __restrict__ qcf,
    float* __restrict__ out)
{
    const int b = blockIdx.x;
    const int t = threadIdx.x;
    const int r = t >> 2;   // row (row step) / col j (col step)
    const int q = t & 3;    // 64-wide chunk

    // overlay region: build {Tl | fq/tq/fc/tc} vs score {plan_s | cf_s}
    __shared__ __align__(16) char ovl[56320];
    __shared__ float ru_s[272], rv_s[272];   // padded: chunk q at q*68
    __shared__ float wsum[16];

    float* Tl = (float*)ovl;                 // 33*33 floats
    int* fq = (int*)(ovl + 4368);
    int* tq = (int*)(ovl + 5392);
    int* fc = (int*)(ovl + 6416);
    int* tc = (int*)(ovl + 7440);
    float* plan_s = (float*)ovl;             // [256][25] f32
    float* cf_s   = (float*)(ovl + 25600);   // [24][16 chunks * 20] f32, swizzled

    // --- phase 1 ---
    for (int i = t; i < 33 * 33; i += 1024) Tl[i] = 0.f;
    if (t < 256) {
        rv_s[PADIDX(t)] = 1.0f;
        int gq = 2 * b, gc = 2 * b + 1;
        int a = NMAXI, bb = NMAXI, c = NMAXI, d = NMAXI;
        if (t < EPG) {
            a  = from_idx[gq * EPG + t] - gq * NPG;
            bb = to_idx  [gq * EPG + t] - gq * NPG;
            c  = from_idx[gc * EPG + t] - gc * NPG;
            d  = to_idx  [gc * EPG + t] - gc * NPG;
        }
        fq[t] = a; tq[t] = bb; fc[t] = c; tc[t] = d;
    }
    __syncthreads();
    {
        int i = t >> 5, j = t & 31;
        Tl[i * 33 + j] = Tplan[((size_t)b << 10) + t];
    }
    __syncthreads();

    // --- build K row chunk (packed bf16): K32[u] = cols (2u, 2u+1) ---
    uint_t K32[32];
    {
        const float* T1 = &Tl[fq[r] * 33];
        const float* T2 = &Tl[tq[r] * 33];
        #pragma unroll
        for (int u = 0; u < 32; ++u) {
            int c0 = q * 64 + 2 * u;
            int f0 = fc[c0], t0 = tc[c0];
            int f1 = fc[c0 + 1], t1 = tc[c0 + 1];
            float la0 = T1[f0] * T2[t0] + T1[t0] * T2[f0];
            float la1 = T1[f1] * T2[t1] + T1[t1] * T2[f1];
            K32[u] = (uint_t)f2bf(exp2f(la0 * L2E_OVER_T))
                   | ((uint_t)f2bf(exp2f(la1 * L2E_OVER_T)) << 16);
        }
    }
    // --- build K^T col chunk (packed bf16): KT32[u] = rows (2u, 2u+1), col r ---
    uint_t KT32[32];
    {
        int j = r;
        int f_ = fc[j], t_ = tc[j];
        #pragma unroll
        for (int u = 0; u < 32; ++u) {
            int i0 = q * 64 + 2 * u;
            const float* A1 = &Tl[fq[i0] * 33];
            const float* A2 = &Tl[tq[i0] * 33];
            float la0 = A1[f_] * A2[t_] + A1[t_] * A2[f_];
            const float* B1 = &Tl[fq[i0 + 1] * 33];
            const float* B2 = &Tl[tq[i0 + 1] * 33];
            float la1 = B1[f_] * B2[t_] + B1[t_] * B2[f_];
            KT32[u] = (uint_t)f2bf(exp2f(la0 * L2E_OVER_T))
                    | ((uint_t)f2bf(exp2f(la1 * L2E_OVER_T)) << 16);
        }
    }

    // --- 20 Sinkhorn iterations, linear domain, all-register packed K ---
    const float4* rv4 = (const float4*)&rv_s[q * 68];
    const float4* ru4 = (const float4*)&ru_s[q * 68];

    for (int it = 0; it < 20; ++it) {
        // row step: U_r = sum_j K[r][j] * rv[j]
        float a0 = 0.f, a1 = 0.f, a2 = 0.f, a3 = 0.f;
        #pragma unroll
        for (int c8 = 0; c8 < 8; ++c8) {
            uint_t k0 = K32[c8 * 4 + 0], k1 = K32[c8 * 4 + 1];
            uint_t k2 = K32[c8 * 4 + 2], k3 = K32[c8 * 4 + 3];
            float4 v0 = rv4[c8 * 2 + 0];
            float4 v1 = rv4[c8 * 2 + 1];
            a0 += bflo(k0) * v0.x; a1 += bfhi(k0) * v0.y;
            a2 += bflo(k1) * v0.z; a3 += bfhi(k1) * v0.w;
            a0 += bflo(k2) * v1.x; a1 += bfhi(k2) * v1.y;
            a2 += bflo(k3) * v1.z; a3 += bfhi(k3) * v1.w;
        }
        float s = (a0 + a1) + (a2 + a3);
        s += __shfl_xor(s, 1);
        s += __shfl_xor(s, 2);
        if (q == 0) ru_s[PADIDX(r)] = frcp(s);
        __syncthreads();
        // col step: V_j = sum_i K[i][j] * ru[i]   (j = r)
        a0 = a1 = a2 = a3 = 0.f;
        #pragma unroll
        for (int c8 = 0; c8 < 8; ++c8) {
            uint_t k0 = KT32[c8 * 4 + 0], k1 = KT32[c8 * 4 + 1];
            uint_t k2 = KT32[c8 * 4 + 2], k3 = KT32[c8 * 4 + 3];
            float4 u0 = ru4[c8 * 2 + 0];
            float4 u1 = ru4[c8 * 2 + 1];
            a0 += bflo(k0) * u0.x; a1 += bfhi(k0) * u0.y;
            a2 += bflo(k1) * u0.z; a3 += bfhi(k1) * u0.w;
            a0 += bflo(k2) * u1.x; a1 += bfhi(k2) * u1.y;
            a2 += bflo(k3) * u1.z; a3 += bfhi(k3) * u1.w;
        }
        s = (a0 + a1) + (a2 + a3);
        s += __shfl_xor(s, 1);
        s += __shfl_xor(s, 2);
        if (q == 0) rv_s[PADIDX(r)] = frcp(s);
        __syncthreads();
    }

    // --- score phase ---
    int nq = qsz[b]; if (nq > 24) nq = 24;
    int nc = csz[b]; if (nc > 24) nc = 24;

    if (q == 0) {   // plan[r][j] = K[r][j] * ru[r] * rv[j], j < 24 (uints 0..11)
        float rr = ru_s[PADIDX(r)];
        #pragma unroll
        for (int u = 0; u < 12; ++u) {
            uint_t kk = K32[u];
            plan_s[r * 25 + 2 * u]     = bflo(kk) * rr * rv_s[2 * u];
            plan_s[r * 25 + 2 * u + 1] = bfhi(kk) * rr * rv_s[2 * u + 1];
        }
    }
    if (t < 768) {  // cf rows -> swizzled LDS chunks of 16 floats @ stride 20
        int j = t >> 5, inner = t & 31;
        int c = inner * 8;
        const float* src = qcf + ((size_t)(2 * b + 1) * 24 + j) * 256 + c;
        float4 v0 = *(const float4*)(src);
        float4 v1 = *(const float4*)(src + 4);
        float* dst = cf_s + j * 320 + (c >> 4) * 20 + (c & 15);
        *(float4*)dst = v0;
        *(float4*)(dst + 4) = v1;
    }
    __syncthreads();

    // thread = 4 rows x 16 cols
    const int rg = t >> 4;
    const int r0 = rg * 4;
    const int m  = t & 15;

    float pc[64];
    #pragma unroll
    for (int i = 0; i < 64; ++i) pc[i] = 0.f;

    for (int j = 0; j < nc; ++j) {
        float p0 = plan_s[(r0 + 0) * 25 + j];
        float p1 = plan_s[(r0 + 1) * 25 + j];
        float p2 = plan_s[(r0 + 2) * 25 + j];
        float p3 = plan_s[(r0 + 3) * 25 + j];
        const float4* cfp = (const float4*)(cf_s + j * 320 + m * 20);
        #pragma unroll
        for (int k = 0; k < 4; ++k) {
            float4 cv = cfp[k];
            pc[ 0 + k * 4 + 0] += p0 * cv.x; pc[ 0 + k * 4 + 1] += p0 * cv.y;
            pc[ 0 + k * 4 + 2] += p0 * cv.z; pc[ 0 + k * 4 + 3] += p0 * cv.w;
            pc[16 + k * 4 + 0] += p1 * cv.x; pc[16 + k * 4 + 1] += p1 * cv.y;
            pc[16 + k * 4 + 2] += p1 * cv.z; pc[16 + k * 4 + 3] += p1 * cv.w;
            pc[32 + k * 4 + 0] += p2 * cv.x; pc[32 + k * 4 + 1] += p2 * cv.y;
            pc[32 + k * 4 + 2] += p2 * cv.z; pc[32 + k * 4 + 3] += p2 * cv.w;
            pc[48 + k * 4 + 0] += p3 * cv.x; pc[48 + k * 4 + 1] += p3 * cv.y;
            pc[48 + k * 4 + 2] += p3 * cv.z; pc[48 + k * 4 + 3] += p3 * cv.w;
        }
    }

    float ssum = 0.f;
    const float* qbase = qcf + (size_t)(2 * b) * 24 * 256;
    #pragma unroll
    for (int i = 0; i < 4; ++i) {
        int row = r0 + i;
        if (row < nq) {
            const float4* qp = (const float4*)(qbase + (size_t)row * 256 + m * 16);
            #pragma unroll
            for (int k = 0; k < 4; ++k) {
                float4 qv = qp[k];
                ssum += fmaxf(qv.x - pc[i * 16 + k * 4 + 0], 0.f);
                ssum += fmaxf(qv.y - pc[i * 16 + k * 4 + 1], 0.f);
                ssum += fmaxf(qv.z - pc[i * 16 + k * 4 + 2], 0.f);
                ssum += fmaxf(qv.w - pc[i * 16 + k * 4 + 3], 0.f);
            }
        } else {
            #pragma unroll
            for (int k = 0; k < 16; ++k) ssum += fmaxf(-pc[i * 16 + k], 0.f);
        }
    }
    ssum += __shfl_xor(ssum, 1);
    ssum += __shfl_xor(ssum, 2);
    ssum += __shfl_xor(ssum, 4);
    ssum += __shfl_xor(ssum, 8);
    ssum += __shfl_xor(ssum, 16);
    ssum += __shfl_xor(ssum, 32);
    if ((t & 63) == 0) wsum[t >> 6] = ssum;
    __syncthreads();
    if (t == 0) {
        float s = 0.f;
        #pragma unroll
        for (int i = 0; i < 16; ++i) s += wsum[i];
        out[b] = -s;
    }
}

// ---------------------------------------------------------------------------
extern "C" void kernel_launch(void* const* d_in, const int* in_sizes, int n_in,
                              void* d_out, int out_size, void* d_ws, size_t ws_size,
                              hipStream_t stream)
{
    const float* edge_feat = (const float*)d_in[0];
    const float* tplan     = (const float*)d_in[1];
    const float* W1        = (const float*)d_in[2];
    const float* b1        = (const float*)d_in[3];
    const float* W2        = (const float*)d_in[4];
    const float* b2        = (const float*)d_in[5];
    const int*   from_idx  = (const int*)d_in[6];
    const int*   to_idx    = (const int*)d_in[7];
    const int*   qsz       = (const int*)d_in[9];
    const int*   csz       = (const int*)d_in[10];
    float* out = (float*)d_out;

    // workspace: [0,128K) W1T bf16 | [128K,256K) W2T bf16 | [256K,+12.6MB) qcf f32
    char* ws = (char*)d_ws;
    ushort_t* W1T = (ushort_t*)ws;
    ushort_t* W2T = W1T + 65536;
    float* qcf = (float*)(ws + 262144);

    prep_w<<<64, 256, 0, stream>>>(W1, W2, W1T, W2T);
    mlp_kernel<<<192, 256, 0, stream>>>(edge_feat, W1T, W2T, b1, b2, qcf);
    sink_kernel<<<256, 1024, 0, stream>>>(tplan, from_idx, to_idx, qsz, csz, qcf, out);
}

// Round 5
// 268.196 us; speedup vs baseline: 1.1654x; 1.1654x over previous
//
#include <hip/hip_runtime.h>

typedef unsigned short ushort_t;
typedef unsigned int uint_t;

typedef float f32x4_t __attribute__((ext_vector_type(4)));
typedef short s16x8_t __attribute__((ext_vector_type(8)));

#define NB   256   // B
#define NG   512   // 2*B graphs
#define NPG  24    // nodes per graph
#define NMAXI 32   // N_MAX
#define EPG  200   // edges per graph
#define DD   256   // feature dim
// 1/TEMPERATURE * log2(e) = 10 * 1.4426950408889634
#define L2E_OVER_T 14.426950408889634f

__device__ __forceinline__ ushort_t f2bf(float f) {
    uint_t u = __float_as_uint(f);
    u += 0x7FFFu + ((u >> 16) & 1u);        // round-to-nearest-even
    return (ushort_t)(u >> 16);
}
__device__ __forceinline__ float bfhi(uint_t u) { return __uint_as_float(u & 0xFFFF0000u); }
__device__ __forceinline__ float bflo(uint_t u) { return __uint_as_float(u << 16); }

__device__ __forceinline__ float frcp(float x) {
#if __has_builtin(__builtin_amdgcn_rcpf)
    return __builtin_amdgcn_rcpf(x);
#else
    return 1.0f / x;
#endif
}

// ---------------------------------------------------------------------------
// Kernel A: W1,W2 -> bf16 transposed ([n][k]), via LDS transpose.
// ---------------------------------------------------------------------------
__global__ __launch_bounds__(256) void prep_w(const float* __restrict__ W1,
                                              const float* __restrict__ W2,
                                              ushort_t* __restrict__ W1T,
                                              ushort_t* __restrict__ W2T)
{
    __shared__ float tile[2][4 * 256];
    const int t = threadIdx.x;
    const int k0 = blockIdx.x * 4;
    #pragma unroll
    for (int i = t; i < 4 * 256; i += 256) {
        tile[0][i] = W1[k0 * 256 + i];
        tile[1][i] = W2[k0 * 256 + i];
    }
    __syncthreads();
    const int n = t;
    #pragma unroll
    for (int m = 0; m < 2; ++m) {
        uint_t p0 = (uint_t)f2bf(tile[m][0 * 256 + n]) | ((uint_t)f2bf(tile[m][1 * 256 + n]) << 16);
        uint_t p1 = (uint_t)f2bf(tile[m][2 * 256 + n]) | ((uint_t)f2bf(tile[m][3 * 256 + n]) << 16);
        ushort_t* dst = (m ? W2T : W1T) + n * 256 + k0;
        uint2 pk; pk.x = p0; pk.y = p1;
        *(uint2*)dst = pk;
    }
}

// ---------------------------------------------------------------------------
// Kernel B: fused 2-layer MLP on the 12288 surviving edge rows (rank < 24).
// ---------------------------------------------------------------------------
__global__ __launch_bounds__(256) void mlp_kernel(
    const float* __restrict__ X, const ushort_t* __restrict__ W1T,
    const ushort_t* __restrict__ W2T, const float* __restrict__ b1,
    const float* __restrict__ b2, float* __restrict__ Y)
{
    __shared__ ushort_t sA[64 * 272];
    const int t = threadIdx.x;
    const int blk = blockIdx.x;
    const int lane = t & 63;
    const int w = t >> 6;
    const int quad = lane >> 4;
    const int mrow = lane & 15;

    {
        int r = t >> 2;
        int ch = (t & 3) * 64;
        int rho = blk * 64 + r;
        int g = rho / NPG;
        int e = rho - g * NPG;
        const float* src = X + ((size_t)(g * EPG + e)) * DD + ch;
        ushort_t* dst = &sA[r * 272 + ch];
        #pragma unroll
        for (int i = 0; i < 8; ++i) {
            float4 v0 = *(const float4*)(src + i * 8);
            float4 v1 = *(const float4*)(src + i * 8 + 4);
            uint4 pk;
            pk.x = (uint_t)f2bf(v0.x) | ((uint_t)f2bf(v0.y) << 16);
            pk.y = (uint_t)f2bf(v0.z) | ((uint_t)f2bf(v0.w) << 16);
            pk.z = (uint_t)f2bf(v1.x) | ((uint_t)f2bf(v1.y) << 16);
            pk.w = (uint_t)f2bf(v1.z) | ((uint_t)f2bf(v1.w) << 16);
            *(uint4*)(dst + i * 8) = pk;
        }
    }
    __syncthreads();

    f32x4_t acc[16];
    #pragma unroll
    for (int i = 0; i < 16; ++i) acc[i] = (f32x4_t){0.f, 0.f, 0.f, 0.f};

    #pragma unroll
    for (int k0 = 0; k0 < 256; k0 += 32) {
        s16x8_t a[4], bb[4];
        #pragma unroll
        for (int mt = 0; mt < 4; ++mt)
            a[mt] = *(const s16x8_t*)&sA[(mt * 16 + mrow) * 272 + k0 + quad * 8];
        #pragma unroll
        for (int nt = 0; nt < 4; ++nt)
            bb[nt] = *(const s16x8_t*)(W1T + (size_t)(64 * w + nt * 16 + mrow) * 256 + k0 + quad * 8);
        #pragma unroll
        for (int mt = 0; mt < 4; ++mt) {
            #pragma unroll
            for (int nt = 0; nt < 4; ++nt)
                acc[mt * 4 + nt] = __builtin_amdgcn_mfma_f32_16x16x32_bf16(
                    a[mt], bb[nt], acc[mt * 4 + nt], 0, 0, 0);
        }
    }
    __syncthreads();

    #pragma unroll
    for (int nt = 0; nt < 4; ++nt) {
        int col = 64 * w + nt * 16 + mrow;
        float bias = b1[col];
        #pragma unroll
        for (int mt = 0; mt < 4; ++mt) {
            f32x4_t v = acc[mt * 4 + nt];
            #pragma unroll
            for (int reg = 0; reg < 4; ++reg) {
                int row = mt * 16 + quad * 4 + reg;
                sA[row * 272 + col] = f2bf(fmaxf(v[reg] + bias, 0.f));
            }
        }
    }
    __syncthreads();

    #pragma unroll
    for (int i = 0; i < 16; ++i) acc[i] = (f32x4_t){0.f, 0.f, 0.f, 0.f};

    #pragma unroll
    for (int k0 = 0; k0 < 256; k0 += 32) {
        s16x8_t a[4], bb[4];
        #pragma unroll
        for (int mt = 0; mt < 4; ++mt)
            a[mt] = *(const s16x8_t*)&sA[(mt * 16 + mrow) * 272 + k0 + quad * 8];
        #pragma unroll
        for (int nt = 0; nt < 4; ++nt)
            bb[nt] = *(const s16x8_t*)(W2T + (size_t)(64 * w + nt * 16 + mrow) * 256 + k0 + quad * 8);
        #pragma unroll
        for (int mt = 0; mt < 4; ++mt) {
            #pragma unroll
            for (int nt = 0; nt < 4; ++nt)
                acc[mt * 4 + nt] = __builtin_amdgcn_mfma_f32_16x16x32_bf16(
                    a[mt], bb[nt], acc[mt * 4 + nt], 0, 0, 0);
        }
    }

    #pragma unroll
    for (int nt = 0; nt < 4; ++nt) {
        int col = 64 * w + nt * 16 + mrow;
        float bias = b2[col];
        #pragma unroll
        for (int mt = 0; mt < 4; ++mt) {
            f32x4_t v = acc[mt * 4 + nt];
            #pragma unroll
            for (int reg = 0; reg < 4; ++reg) {
                int row = blk * 64 + mt * 16 + quad * 4 + reg;
                Y[(size_t)row * 256 + col] = v[reg] + bias;
            }
        }
    }
}

// ---------------------------------------------------------------------------
// Kernel C: per-b fused K-build -> 20x linear-domain Sinkhorn -> score.
// TILE layout: thread (R = t>>4, C = t&15) owns the 4x16 tile of K
//   rows 4R..4R+3, cols 16C..16C+15, packed bf16 in Kp[4][8] (32 uints).
// One copy serves both directions:
//   row step: partial over 16 cols, shfl_xor(1,2,4,8) over C lanes (in-wave)
//   col step: partial over 4 rows, shfl_xor(16,32) over R (in-wave) + LDS Vp
// Persistent state ~55 VGPR -> fits the 64-reg budget (2 blocks/CU), no scratch.
// ---------------------------------------------------------------------------
__global__ __launch_bounds__(1024) void sink_kernel(
    const float* __restrict__ Tplan, const int* __restrict__ from_idx,
    const int* __restrict__ to_idx, const int* __restrict__ qsz,
    const int* __restrict__ csz, const float* __restrict__ qcf,
    float* __restrict__ out)
{
    const int b = blockIdx.x;
    const int t = threadIdx.x;
    const int R = t >> 4;      // row group: rows 4R..4R+3
    const int C = t & 15;      // col group: cols 16C..16C+15
    const int w = t >> 6;      // wave id (rows 16w..16w+15 live in wave w)

    // overlay region (phase-disjoint):
    //  build: Tl (33*33 f) @0, fq/tq/fc/tc @4368/5392/6416/7440
    //  iters: Vp [16][272] f @0 (17408 B)
    //  score: plan_s [256][25] f @0, cf_s @25600 ([24][16*20] swizzled)
    __shared__ __align__(16) char ovl[56320];
    __shared__ float ru_s[260];
    __shared__ float rv_p[320];    // col chunk C at rv_p[20C..20C+15] (b128-aligned)
    __shared__ float wsum[16];

    float* Tl = (float*)ovl;
    int* fq = (int*)(ovl + 4368);
    int* tq = (int*)(ovl + 5392);
    int* fc = (int*)(ovl + 6416);
    int* tc = (int*)(ovl + 7440);
    float* Vp = (float*)ovl;               // [16][272]
    float* plan_s = (float*)ovl;           // [256][25]
    float* cf_s   = (float*)(ovl + 25600);

    // --- phase 1: init ---
    for (int i = t; i < 33 * 33; i += 1024) Tl[i] = 0.f;
    if (t < 320) rv_p[t] = 1.0f;
    if (t < 256) {
        int gq = 2 * b, gc = 2 * b + 1;
        int a = NMAXI, bb = NMAXI, c = NMAXI, d = NMAXI;
        if (t < EPG) {
            a  = from_idx[gq * EPG + t] - gq * NPG;
            bb = to_idx  [gq * EPG + t] - gq * NPG;
            c  = from_idx[gc * EPG + t] - gc * NPG;
            d  = to_idx  [gc * EPG + t] - gc * NPG;
        }
        fq[t] = a; tq[t] = bb; fc[t] = c; tc[t] = d;
    }
    __syncthreads();
    {
        int i = t >> 5, j = t & 31;
        Tl[i * 33 + j] = Tplan[((size_t)b << 10) + t];
    }
    __syncthreads();

    // --- build K tile: Kp[i][u] packs cols (16C+2u, 16C+2u+1) of row 4R+i ---
    uint_t Kp[4][8];
    {
        int fcl[16], tcl[16];
        #pragma unroll
        for (int o = 0; o < 16; ++o) { fcl[o] = fc[16 * C + o]; tcl[o] = tc[16 * C + o]; }
        #pragma unroll
        for (int i = 0; i < 4; ++i) {
            const float* T1 = &Tl[fq[4 * R + i] * 33];
            const float* T2 = &Tl[tq[4 * R + i] * 33];
            #pragma unroll
            for (int u = 0; u < 8; ++u) {
                int f0 = fcl[2 * u], t0 = tcl[2 * u];
                int f1 = fcl[2 * u + 1], t1 = tcl[2 * u + 1];
                float la0 = T1[f0] * T2[t0] + T1[t0] * T2[f0];
                float la1 = T1[f1] * T2[t1] + T1[t1] * T2[f1];
                Kp[i][u] = (uint_t)f2bf(exp2f(la0 * L2E_OVER_T))
                         | ((uint_t)f2bf(exp2f(la1 * L2E_OVER_T)) << 16);
            }
        }
    }

    // --- 20 Sinkhorn iterations ---
    for (int it = 0; it < 20; ++it) {
        // row step: U_r = sum_j K[r][j] * rv[j]
        {
            float4 rv0 = *(const float4*)&rv_p[20 * C + 0];
            float4 rv1 = *(const float4*)&rv_p[20 * C + 4];
            float4 rv2 = *(const float4*)&rv_p[20 * C + 8];
            float4 rv3 = *(const float4*)&rv_p[20 * C + 12];
            float pr[4];
            #pragma unroll
            for (int i = 0; i < 4; ++i) {
                float a0 = bflo(Kp[i][0]) * rv0.x + bfhi(Kp[i][0]) * rv0.y;
                float a1 = bflo(Kp[i][1]) * rv0.z + bfhi(Kp[i][1]) * rv0.w;
                float a2 = bflo(Kp[i][2]) * rv1.x + bfhi(Kp[i][2]) * rv1.y;
                float a3 = bflo(Kp[i][3]) * rv1.z + bfhi(Kp[i][3]) * rv1.w;
                a0 += bflo(Kp[i][4]) * rv2.x + bfhi(Kp[i][4]) * rv2.y;
                a1 += bflo(Kp[i][5]) * rv2.z + bfhi(Kp[i][5]) * rv2.w;
                a2 += bflo(Kp[i][6]) * rv3.x + bfhi(Kp[i][6]) * rv3.y;
                a3 += bflo(Kp[i][7]) * rv3.z + bfhi(Kp[i][7]) * rv3.w;
                pr[i] = (a0 + a1) + (a2 + a3);
            }
            #pragma unroll
            for (int i = 0; i < 4; ++i) {
                float s = pr[i];
                s += __shfl_xor(s, 1);
                s += __shfl_xor(s, 2);
                s += __shfl_xor(s, 4);
                s += __shfl_xor(s, 8);
                pr[i] = s;
            }
            if (C == 0) {
                #pragma unroll
                for (int i = 0; i < 4; ++i) ru_s[4 * R + i] = frcp(pr[i]);
            }
        }
        __syncthreads();
        // col step: V_j = sum_i K[i][j] * ru[i]
        {
            float u0 = ru_s[4 * R + 0], u1 = ru_s[4 * R + 1];
            float u2 = ru_s[4 * R + 2], u3 = ru_s[4 * R + 3];
            float pc[16];
            #pragma unroll
            for (int u = 0; u < 8; ++u) {
                float e0 = bflo(Kp[0][u]) * u0 + bflo(Kp[1][u]) * u1
                         + bflo(Kp[2][u]) * u2 + bflo(Kp[3][u]) * u3;
                float e1 = bfhi(Kp[0][u]) * u0 + bfhi(Kp[1][u]) * u1
                         + bfhi(Kp[2][u]) * u2 + bfhi(Kp[3][u]) * u3;
                pc[2 * u] = e0; pc[2 * u + 1] = e1;
            }
            #pragma unroll
            for (int k = 0; k < 16; ++k) {
                float s = pc[k];
                s += __shfl_xor(s, 16);
                s += __shfl_xor(s, 32);
                pc[k] = s;
            }
            if ((t & 63) < 16) {   // one lane per C in this wave holds 16-row sums
                float* dst = &Vp[w * 272 + C * 16];
                *(float4*)(dst + 0)  = (float4){pc[0], pc[1], pc[2], pc[3]};
                *(float4*)(dst + 4)  = (float4){pc[4], pc[5], pc[6], pc[7]};
                *(float4*)(dst + 8)  = (float4){pc[8], pc[9], pc[10], pc[11]};
                *(float4*)(dst + 12) = (float4){pc[12], pc[13], pc[14], pc[15]};
            }
        }
        __syncthreads();
        if (t < 256) {   // second stage: sum the 16 wave partials
            float s = 0.f;
            #pragma unroll
            for (int ww = 0; ww < 16; ++ww) s += Vp[ww * 272 + t];
            rv_p[(t >> 4) * 20 + (t & 15)] = frcp(s);
        }
        __syncthreads();
    }

    // --- plan: plan_s[r][j] = K[r][j] * ru[r] * rv[j], j < 24 ---
    int nq = qsz[b]; if (nq > 24) nq = 24;
    int nc = csz[b]; if (nc > 24) nc = 24;

    if (C < 2) {
        int umax = (C == 0) ? 8 : 4;   // C=0: cols 0..15; C=1: cols 16..23
        #pragma unroll
        for (int i = 0; i < 4; ++i) {
            float rr = ru_s[4 * R + i];
            for (int u = 0; u < umax; ++u) {
                int j = 16 * C + 2 * u;
                plan_s[(4 * R + i) * 25 + j]     = bflo(Kp[i][u]) * rr * rv_p[20 * C + 2 * u];
                plan_s[(4 * R + i) * 25 + j + 1] = bfhi(Kp[i][u]) * rr * rv_p[20 * C + 2 * u + 1];
            }
        }
    }
    if (t < 768) {  // cf rows -> swizzled LDS chunks of 16 floats @ stride 20
        int j = t >> 5, inner = t & 31;
        int c = inner * 8;
        const float* src = qcf + ((size_t)(2 * b + 1) * 24 + j) * 256 + c;
        float4 v0 = *(const float4*)(src);
        float4 v1 = *(const float4*)(src + 4);
        float* dst = cf_s + j * 320 + (c >> 4) * 20 + (c & 15);
        *(float4*)dst = v0;
        *(float4*)(dst + 4) = v1;
    }
    __syncthreads();

    // --- score: thread = rows 4R..4R+3 x cols 16C..16C+15 ---
    const int r0 = R * 4;
    const int m  = C;

    float pc[64];
    #pragma unroll
    for (int i = 0; i < 64; ++i) pc[i] = 0.f;

    for (int j = 0; j < nc; ++j) {
        float p0 = plan_s[(r0 + 0) * 25 + j];
        float p1 = plan_s[(r0 + 1) * 25 + j];
        float p2 = plan_s[(r0 + 2) * 25 + j];
        float p3 = plan_s[(r0 + 3) * 25 + j];
        const float4* cfp = (const float4*)(cf_s + j * 320 + m * 20);
        #pragma unroll
        for (int k = 0; k < 4; ++k) {
            float4 cv = cfp[k];
            pc[ 0 + k * 4 + 0] += p0 * cv.x; pc[ 0 + k * 4 + 1] += p0 * cv.y;
            pc[ 0 + k * 4 + 2] += p0 * cv.z; pc[ 0 + k * 4 + 3] += p0 * cv.w;
            pc[16 + k * 4 + 0] += p1 * cv.x; pc[16 + k * 4 + 1] += p1 * cv.y;
            pc[16 + k * 4 + 2] += p1 * cv.z; pc[16 + k * 4 + 3] += p1 * cv.w;
            pc[32 + k * 4 + 0] += p2 * cv.x; pc[32 + k * 4 + 1] += p2 * cv.y;
            pc[32 + k * 4 + 2] += p2 * cv.z; pc[32 + k * 4 + 3] += p2 * cv.w;
            pc[48 + k * 4 + 0] += p3 * cv.x; pc[48 + k * 4 + 1] += p3 * cv.y;
            pc[48 + k * 4 + 2] += p3 * cv.z; pc[48 + k * 4 + 3] += p3 * cv.w;
        }
    }

    float ssum = 0.f;
    const float* qbase = qcf + (size_t)(2 * b) * 24 * 256;
    #pragma unroll
    for (int i = 0; i < 4; ++i) {
        int row = r0 + i;
        if (row < nq) {
            const float4* qp = (const float4*)(qbase + (size_t)row * 256 + m * 16);
            #pragma unroll
            for (int k = 0; k < 4; ++k) {
                float4 qv = qp[k];
                ssum += fmaxf(qv.x - pc[i * 16 + k * 4 + 0], 0.f);
                ssum += fmaxf(qv.y - pc[i * 16 + k * 4 + 1], 0.f);
                ssum += fmaxf(qv.z - pc[i * 16 + k * 4 + 2], 0.f);
                ssum += fmaxf(qv.w - pc[i * 16 + k * 4 + 3], 0.f);
            }
        } else {
            #pragma unroll
            for (int k = 0; k < 16; ++k) ssum += fmaxf(-pc[i * 16 + k], 0.f);
        }
    }
    ssum += __shfl_xor(ssum, 1);
    ssum += __shfl_xor(ssum, 2);
    ssum += __shfl_xor(ssum, 4);
    ssum += __shfl_xor(ssum, 8);
    ssum += __shfl_xor(ssum, 16);
    ssum += __shfl_xor(ssum, 32);
    if ((t & 63) == 0) wsum[t >> 6] = ssum;
    __syncthreads();
    if (t == 0) {
        float s = 0.f;
        #pragma unroll
        for (int i = 0; i < 16; ++i) s += wsum[i];
        out[b] = -s;
    }
}

// ---------------------------------------------------------------------------
extern "C" void kernel_launch(void* const* d_in, const int* in_sizes, int n_in,
                              void* d_out, int out_size, void* d_ws, size_t ws_size,
                              hipStream_t stream)
{
    const float* edge_feat = (const float*)d_in[0];
    const float* tplan     = (const float*)d_in[1];
    const float* W1        = (const float*)d_in[2];
    const float* b1        = (const float*)d_in[3];
    const float* W2        = (const float*)d_in[4];
    const float* b2        = (const float*)d_in[5];
    const int*   from_idx  = (const int*)d_in[6];
    const int*   to_idx    = (const int*)d_in[7];
    const int*   qsz       = (const int*)d_in[9];
    const int*   csz       = (const int*)d_in[10];
    float* out = (float*)d_out;

    // workspace: [0,128K) W1T bf16 | [128K,256K) W2T bf16 | [256K,+12.6MB) qcf f32
    char* ws = (char*)d_ws;
    ushort_t* W1T = (ushort_t*)ws;
    ushort_t* W2T = W1T + 65536;
    float* qcf = (float*)(ws + 262144);

    prep_w<<<64, 256, 0, stream>>>(W1, W2, W1T, W2T);
    mlp_kernel<<<192, 256, 0, stream>>>(edge_feat, W1T, W2T, b1, b2, qcf);
    sink_kernel<<<256, 1024, 0, stream>>>(tplan, from_idx, to_idx, qsz, csz, qcf, out);
}